// Round 7
// baseline (400.494 us; speedup 1.0000x reference)
//
#include <hip/hip_runtime.h>

using f32x4  = __attribute__((ext_vector_type(4))) float;
using bf16x8 = __attribute__((ext_vector_type(8))) short;

#define SEQ 1025
#define NH  12

__device__ __forceinline__ unsigned short f2bf(float f) {
  unsigned u = __float_as_uint(f);
  u += 0x7FFFu + ((u >> 16) & 1u);        // RNE; inputs are finite
  return (unsigned short)(u >> 16);
}

// cheap round-to-nearest (ties up) for P values (p >= 0, feeds PV MFMA)
__device__ __forceinline__ unsigned short f2bf_p(float f) {
  return (unsigned short)((__float_as_uint(f) + 0x8000u) >> 16);
}

__device__ __forceinline__ void async16(const void* g, void* s) {
  __builtin_amdgcn_global_load_lds(
      (const __attribute__((address_space(1))) void*)g,
      (__attribute__((address_space(3))) void*)s, 16, 0, 0);
}

// ================= device bodies (shared by standalone & merged kernels) ====

// ---- X fp32 -> bf16, padded to 8320 rows (zeros) ----
__device__ __forceinline__ void conv_x_body(int bx, const float* __restrict__ X,
                                            ushort* __restrict__ Xb) {
  int t = bx * 256 + threadIdx.x;
  if (t >= 8320 * 96) return;
  int row = t / 96;
  size_t e = (size_t)t * 8;
  union { uint4 q; ushort us[8]; } o;
  if (row < 8200) {
    float4 f0 = *(const float4*)(X + e);
    float4 f1 = *(const float4*)(X + e + 4);
    o.us[0] = f2bf(f0.x); o.us[1] = f2bf(f0.y); o.us[2] = f2bf(f0.z); o.us[3] = f2bf(f0.w);
    o.us[4] = f2bf(f1.x); o.us[5] = f2bf(f1.y); o.us[6] = f2bf(f1.z); o.us[7] = f2bf(f1.w);
  } else {
    o.q = make_uint4(0, 0, 0, 0);
  }
  *(uint4*)(Xb + e) = o.q;
}

// ---- W[q|k|v] fp32 -> Wt [N=2304][K=768] bf16 (+ bias fold) ----
__device__ __forceinline__ void pack_w_body(int j, const float* __restrict__ Wq,
                                            const float* __restrict__ Wk,
                                            const float* __restrict__ Wv,
                                            ushort* __restrict__ Wt,
                                            const float* __restrict__ bq,
                                            const float* __restrict__ bk,
                                            const float* __restrict__ bv,
                                            float* __restrict__ bc,
                                            float (*tile)[33]) {
  const int nt = j % 72;                       // 0..71
  const int kt = j / 72;                       // 0..23
  if (kt == 0 && nt < 9) {                     // folded bias concat
    int t2 = nt * 256 + threadIdx.x;
    if (t2 < 768) bc[t2] = bq[t2];
    else if (t2 < 1536) bc[t2] = bk[t2 - 768];
    else if (t2 < 2304) bc[t2] = bv[t2 - 1536];
  }
  const int sel = nt / 24;
  const int o0 = (nt - sel * 24) * 32;
  const int k0 = kt * 32;
  const float* W = sel == 0 ? Wq : sel == 1 ? Wk : Wv;
  const int t = threadIdx.x;
  const int x = t & 31, y = t >> 5;
  for (int p = 0; p < 4; ++p)
    tile[y + p * 8][x] = W[(size_t)(k0 + y + p * 8) * 768 + o0 + x];
  __syncthreads();
  for (int p = 0; p < 4; ++p) {
    const int nl = y + p * 8;
    Wt[(size_t)(nt * 32 + nl) * 768 + k0 + x] = f2bf(tile[x][nl]);
  }
}

// ---- rel_bias repack: [H][S][S] -> MFMA C-frag order -----------------------
// biasF[h][kt=17][w16=72][lane=64][e=16], e=ct*4+r2, pre-scaled by log2(e),
// cols>1024 pre-masked to -3e30.
__device__ __forceinline__ void repack_body(int id, const float* __restrict__ rel,
                                            float* __restrict__ bf,
                                            float (*lds)[580]) {
  const int half = id & 1;
  const int hw = id >> 1;
  const int h = hw / 72, w = hw - h * 72;
  const int t = threadIdx.x;
  const int W = half ? 512 : 576;              // kt 9..16 : kt 0..8
  const int cbase = half * 576;
  const float* src = rel + (size_t)h * SEQ * SEQ;
  for (int r = 0; r < 16; ++r) {
    int q = w * 16 + r; if (q > 1024) q = 1024;
    const float* row = src + (size_t)q * SEQ;
    for (int c = t; c < W; c += 256) {
      int col = cbase + c;
      lds[r][c] = (col <= 1024) ? row[col] * 1.44269504f : -3.0e30f;
    }
  }
  __syncthreads();
  const int lane = t >> 2, ct = t & 3;
  const int l16 = lane & 15, quad = lane >> 4;
  const int nkt = half ? 8 : 9;
  for (int ktl = 0; ktl < nkt; ++ktl) {
    const int kt = half * 9 + ktl;
    const int col = ktl * 64 + ct * 16 + l16;
    f32x4 v;
    v[0] = lds[quad * 4 + 0][col];
    v[1] = lds[quad * 4 + 1][col];
    v[2] = lds[quad * 4 + 2][col];
    v[3] = lds[quad * 4 + 3][col];
    *(f32x4*)(bf + (((size_t)h * 17 + kt) * 72 + w) * 1024 + lane * 16 + ct * 4) = v;
  }
}

// ---- fused QKV GEMM: [8320x768]*[768x2304] -> Q/K/V [B,H,S,64] bf16 --------
// smem layout: a_sm[0,8192) b_sm[8192,16384) c_sm[16384,33792)
__device__ __forceinline__ void gemm_body(int mb, int nb,
                                          const ushort* __restrict__ A,
                                          const ushort* __restrict__ Bt,
                                          const float* __restrict__ bias,
                                          ushort* __restrict__ Qo,
                                          ushort* __restrict__ Ko,
                                          ushort* __restrict__ Vo,
                                          char* smem) {
  ushort* a_sm = (ushort*)smem;
  ushort* b_sm = (ushort*)(smem + 8192);
  ushort* c_sm = (ushort*)(smem + 16384);      // 64 x 136
  const int t = threadIdx.x;
  const int lane = t & 63, wave = t >> 6;
  const int quad = lane >> 4, l16 = lane & 15;
  const int wrow = wave >> 1, wcol = wave & 1;
  const int m0 = mb * 128, n0 = nb * 128;

  f32x4 acc[4][4] = {};

  const ushort* a_g = A + (size_t)m0 * 768;
  const ushort* b_g = Bt + (size_t)n0 * 768;

  for (int k0 = 0; k0 < 768; k0 += 32) {
    __syncthreads();
    for (int r = 0; r < 2; ++r) {
      int c = r * 256 + t;
      int row = c >> 2;
      int colb = (c & 3) * 16;
      async16((const char*)(a_g + (size_t)row * 768 + k0) + colb, (char*)a_sm + c * 16);
      async16((const char*)(b_g + (size_t)row * 768 + k0) + colb, (char*)b_sm + c * 16);
    }
    __syncthreads();
    bf16x8 af[4], bfr[4];
    for (int i = 0; i < 4; ++i) {
      af[i]  = *(const bf16x8*)(a_sm + (wrow * 64 + i * 16 + l16) * 32 + quad * 8);
      bfr[i] = *(const bf16x8*)(b_sm + (wcol * 64 + i * 16 + l16) * 32 + quad * 8);
    }
    for (int i = 0; i < 4; ++i)
      for (int j = 0; j < 4; ++j)
        acc[i][j] = __builtin_amdgcn_mfma_f32_16x16x32_bf16(af[i], bfr[j], acc[i][j], 0, 0, 0);
  }

  // epilogue: n-tile (128) lies in one of Q/K/V and spans 2 heads
  const int sel = n0 / 768;
  const int o0 = n0 - sel * 768;
  const int hh0 = o0 >> 6;
  ushort* dst = sel == 0 ? Qo : sel == 1 ? Ko : Vo;
  float bvj[4];
  for (int j = 0; j < 4; ++j) bvj[j] = bias[n0 + wcol * 64 + j * 16 + l16];

  for (int p = 0; p < 2; ++p) {
    __syncthreads();
    if (wrow == p) {
      for (int i = 0; i < 4; ++i)
        for (int j = 0; j < 4; ++j)
          for (int r = 0; r < 4; ++r)
            c_sm[(i * 16 + quad * 4 + r) * 136 + wcol * 64 + j * 16 + l16] =
                f2bf(acc[i][j][r] + bvj[j]);
    }
    __syncthreads();
    const int head = t >> 7;
    const int ci = t & 127;
    for (int k = 0; k < 4; ++k) {
      int ch = ci + 128 * k;
      int row = ch >> 3, off = (ch & 7) * 8;
      int gm = m0 + p * 64 + row;
      if (gm < 8200) {
        int bb = gm / 1025, ss = gm - bb * 1025;
        uint4 v = *(const uint4*)(c_sm + row * 136 + head * 64 + off);
        *(uint4*)(dst + (((size_t)(bb * NH + hh0 + head) * SEQ + ss) << 6) + off) = v;
      }
    }
  }
}

// ================= kernels ==================================================

// prep: conv_x (3120 blocks) + pack_w/bias fold (1728 blocks)
__global__ __launch_bounds__(256) void prep(const float* __restrict__ X,
                                            ushort* __restrict__ Xb,
                                            const float* __restrict__ Wq,
                                            const float* __restrict__ Wk,
                                            const float* __restrict__ Wv,
                                            ushort* __restrict__ Wt,
                                            const float* __restrict__ bq,
                                            const float* __restrict__ bk,
                                            const float* __restrict__ bv,
                                            float* __restrict__ bc) {
  __shared__ __align__(16) float tile[32][33];
  const int bx = blockIdx.x;
  if (bx < 3120) conv_x_body(bx, X, Xb);
  else pack_w_body(bx - 3120, Wq, Wk, Wv, Wt, bq, bk, bv, bc, tile);
}

// merged gemm (1170 blocks) + bias repack (1728 blocks): repack's pure-memory
// blocks fill gemm's idle memory slots (layout A, needs ws >= 114.3 MB)
__global__ __launch_bounds__(256, 4) void gemm_repack(
    const ushort* __restrict__ A, const ushort* __restrict__ Bt,
    const float* __restrict__ biasc, ushort* __restrict__ Qo,
    ushort* __restrict__ Ko, ushort* __restrict__ Vo,
    const float* __restrict__ rel, float* __restrict__ bf) {
  __shared__ __align__(16) char smem[37120];
  const int bx = blockIdx.x;
  if (bx < 1170) gemm_body(bx % 65, bx / 65, A, Bt, biasc, Qo, Ko, Vo, smem);
  else repack_body(bx - 1170, rel, bf, (float(*)[580])smem);
}

// standalone fallbacks (layout B: biasF overlays Xb -> repack must follow gemm)
__global__ __launch_bounds__(256) void gemm_qkv_k(const ushort* __restrict__ A,
                                                  const ushort* __restrict__ Bt,
                                                  const float* __restrict__ biasc,
                                                  ushort* __restrict__ Qo,
                                                  ushort* __restrict__ Ko,
                                                  ushort* __restrict__ Vo) {
  __shared__ __align__(16) char smem[33792];
  gemm_body(blockIdx.x, blockIdx.y, A, Bt, biasc, Qo, Ko, Vo, smem);
}

__global__ __launch_bounds__(256, 4) void repack_k(const float* __restrict__ rel,
                                                   float* __restrict__ bf) {
  __shared__ __align__(16) float lds[16][580];
  repack_body(blockIdx.x, rel, bf, lds);
}

// ---------------- flash attention v6: + bias register prefetch --------------
// block = 4 waves, one (b,h), 128 q-rows, k-tile 64, 17 iters. K/V AND bias
// register-prefetched one tile ahead (bias latency was the per-iter critical
// path). LDS: p 4x[32][72] | K [64][72] | V^T [64][72] = 36864 -> 4 blk/CU.
__global__ __launch_bounds__(256, 4) void attn(const ushort* __restrict__ Qb,
                                               const ushort* __restrict__ Kb,
                                               const ushort* __restrict__ Vb,
                                               const float* __restrict__ biasF,
                                               float* __restrict__ out) {
  __shared__ __align__(16) char smem[36864];
  ushort* p_sm = (ushort*)smem;                 // 4 x [32][72]
  ushort* k_sm = (ushort*)(smem + 18432);       // [64][72]
  ushort* v_sm = (ushort*)(smem + 27648);       // [64][72] transposed [hd][k]

  const int t = threadIdx.x;
  const int lane = t & 63, wave = t >> 6;
  const int quad = lane >> 4, l16 = lane & 15;

  const int id = blockIdx.x;                    // [0,864)
  const int x = id & 7, s = id >> 3;            // XCD swizzle
  const int Gg = s / 9, qt = s - Gg * 9;
  const int G = Gg * 8 + x;                     // (b,h) group
  const int b = G / 12, h = G - b * 12;
  const int q0 = qt * 128;

  const size_t bh = (size_t)(b * NH + h) * SEQ * 64;
  const ushort* Qp = Qb + bh;
  const ushort* Kp = Kb + bh;
  const ushort* Vp = Vb + bh;

  uint4 kpre0, kpre1, vpre0, vpre1;
  const int vkp2 = t & 31, vhb = (t >> 5) * 8;

  auto issue_kv = [&](int kb) {
    {
      int c = t, row = c >> 3, cb = (c & 7) * 8;
      int rk = kb + row; if (rk > 1024) rk = 1024;
      kpre0 = *(const uint4*)(Kp + (size_t)rk * 64 + cb);
    }
    {
      int c = t + 256, row = c >> 3, cb = (c & 7) * 8;
      int rk = kb + row; if (rk > 1024) rk = 1024;
      kpre1 = *(const uint4*)(Kp + (size_t)rk * 64 + cb);
    }
    {
      int r0 = kb + vkp2 * 2;
      int r0c = r0 > 1024 ? 1024 : r0;
      int r1c = r0 + 1 > 1024 ? 1024 : r0 + 1;
      vpre0 = *(const uint4*)(Vp + (size_t)r0c * 64 + vhb);
      vpre1 = *(const uint4*)(Vp + (size_t)r1c * 64 + vhb);
    }
  };

  const float* bf_base = biasF +
      ((size_t)h * 17 * 72 + (qt * 8 + wave * 2)) * 1024 + (lane << 4);

  issue_kv(0);
  f32x4 brp[2][4];                              // bias prefetch (C-frag order)
  for (int rt = 0; rt < 2; ++rt)
    for (int ct = 0; ct < 4; ++ct)
      brp[rt][ct] = *(const f32x4*)(bf_base + rt * 1024 + ct * 4);

  ushort* pw = p_sm + wave * (32 * 72);
  const int qbase = q0 + wave * 32;
  for (int i = 0; i < 4; ++i) {
    int c = lane + 64 * i;
    int row = c >> 3, cb = (c & 7) * 8;
    int rq = qbase + row; if (rq > 1024) rq = 1024;
    *(uint4*)(pw + row * 72 + cb) = *(const uint4*)(Qp + (size_t)rq * 64 + cb);
  }
  bf16x8 qf[2][2];
  for (int rt = 0; rt < 2; ++rt)
    for (int ks = 0; ks < 2; ++ks)
      qf[rt][ks] = *(const bf16x8*)(pw + (rt * 16 + l16) * 72 + ks * 32 + quad * 8);

  float lst[8] = {0, 0, 0, 0, 0, 0, 0, 0};
  f32x4 oacc[2][4] = {};
  const float c_scale = 0.18033688f;            // (1/8) * log2(e)

  for (int kt = 0; kt < 17; ++kt) {
    __syncthreads();
    {
      int c = t;
      *(uint4*)(k_sm + (c >> 3) * 72 + (c & 7) * 8) = kpre0;
      c = t + 256;
      *(uint4*)(k_sm + (c >> 3) * 72 + (c & 7) * 8) = kpre1;
    }
    {
      union { uint4 q; ushort us[8]; } e0, e1;
      e0.q = vpre0; e1.q = vpre1;
      for (int e = 0; e < 8; ++e)
        *(unsigned*)(v_sm + (vhb + e) * 72 + vkp2 * 2) =
            (unsigned)e0.us[e] | ((unsigned)e1.us[e] << 16);
    }
    __syncthreads();

    if (kt < 16) issue_kv(kt * 64 + 64);        // K/V for kt+1 in flight

    f32x4 sc[2][4] = {};
    for (int ct = 0; ct < 4; ++ct)
      for (int ks = 0; ks < 2; ++ks) {
        bf16x8 kf = *(const bf16x8*)(k_sm + (ct * 16 + l16) * 72 + ks * 32 + quad * 8);
        sc[0][ct] = __builtin_amdgcn_mfma_f32_16x16x32_bf16(qf[0][ks], kf, sc[0][ct], 0, 0, 0);
        sc[1][ct] = __builtin_amdgcn_mfma_f32_16x16x32_bf16(qf[1][ks], kf, sc[1][ct], 0, 0, 0);
      }

    // p = exp2(sc*scale + bias); accumulate l; write P (consumes brp)
    for (int rt = 0; rt < 2; ++rt)
      for (int ct = 0; ct < 4; ++ct)
        for (int r2 = 0; r2 < 4; ++r2) {
          float p = __builtin_amdgcn_exp2f(
              fmaf(sc[rt][ct][r2], c_scale, brp[rt][ct][r2]));
          lst[rt * 4 + r2] += p;
          pw[(rt * 16 + quad * 4 + r2) * 72 + ct * 16 + l16] = f2bf_p(p);
        }

    if (kt < 16) {                              // bias for kt+1 in flight
      const float* bfp = bf_base + (size_t)(kt + 1) * (72 * 1024);
      for (int rt = 0; rt < 2; ++rt)
        for (int ct = 0; ct < 4; ++ct)
          brp[rt][ct] = *(const f32x4*)(bfp + rt * 1024 + ct * 4);
    }

    for (int ks = 0; ks < 2; ++ks) {
      bf16x8 pf0 = *(const bf16x8*)(pw + l16 * 72 + ks * 32 + quad * 8);
      bf16x8 pf1 = *(const bf16x8*)(pw + (16 + l16) * 72 + ks * 32 + quad * 8);
      for (int c4 = 0; c4 < 4; ++c4) {
        bf16x8 vf = *(const bf16x8*)(v_sm + (c4 * 16 + l16) * 72 + ks * 32 + quad * 8);
        oacc[0][c4] = __builtin_amdgcn_mfma_f32_16x16x32_bf16(pf0, vf, oacc[0][c4], 0, 0, 0);
        oacc[1][c4] = __builtin_amdgcn_mfma_f32_16x16x32_bf16(pf1, vf, oacc[1][c4], 0, 0, 0);
      }
    }
  }

  for (int si = 0; si < 8; ++si) {
    float s2 = lst[si];
    s2 += __shfl_xor(s2, 1);
    s2 += __shfl_xor(s2, 2);
    s2 += __shfl_xor(s2, 4);
    s2 += __shfl_xor(s2, 8);
    lst[si] = s2;
  }
  for (int rt = 0; rt < 2; ++rt)
    for (int r2 = 0; r2 < 4; ++r2) {
      int sr = qbase + rt * 16 + quad * 4 + r2;
      if (sr < SEQ) {
        float inv = 1.0f / lst[rt * 4 + r2];
        float* op = out + ((size_t)b * SEQ + sr) * 768 + h * 64;
        for (int c4 = 0; c4 < 4; ++c4)
          op[c4 * 16 + l16] = oacc[rt][c4][r2] * inv;
      }
    }
}

// ---------------- launch ----------------
extern "C" void kernel_launch(void* const* d_in, const int* in_sizes, int n_in,
                              void* d_out, int out_size, void* d_ws, size_t ws_size,
                              hipStream_t stream) {
  const float* X  = (const float*)d_in[0];
  const float* rb = (const float*)d_in[1];
  const float* Wq = (const float*)d_in[2];
  const float* bq = (const float*)d_in[3];
  const float* Wk = (const float*)d_in[4];
  const float* bk = (const float*)d_in[5];
  const float* Wv = (const float*)d_in[6];
  const float* bv = (const float*)d_in[7];
  float* out = (float*)d_out;
  char* ws = (char*)d_ws;

  ushort* Qb    = (ushort*)ws;                          // 12,595,200 B
  ushort* Kb    = (ushort*)(ws + 12595200);
  ushort* Vb    = (ushort*)(ws + 25190400);             // ends 37,785,600
  ushort* Xb    = (ushort*)(ws + 37785600);             // 12,779,520 -> 50,565,120
  ushort* Wt    = (ushort*)(ws + 50565120);             //  3,538,944 -> 54,104,064
  float*  biasc = (float*)(ws + 54104064);              //      9,216 -> 54,113,280

  const bool bigws = ws_size >= 114275328ULL;
  // layout A: biasF in fresh space (repack can overlap gemm);
  // layout B: biasF overlays Xb/Wt (dead after gemm) -> repack after gemm.
  float* biasF = bigws ? (float*)(ws + 54113280) : (float*)(ws + 37785600);

  prep<<<3120 + 1728, 256, 0, stream>>>(X, Xb, Wq, Wk, Wv, Wt, bq, bk, bv, biasc);
  if (bigws) {
    gemm_repack<<<1170 + 1728, 256, 0, stream>>>(Xb, Wt, biasc, Qb, Kb, Vb, rb, biasF);
  } else {
    gemm_qkv_k<<<dim3(65, 18), 256, 0, stream>>>(Xb, Wt, biasc, Qb, Kb, Vb);
    repack_k<<<NH * 72 * 2, 256, 0, stream>>>(rb, biasF);
  }
  attn<<<864, 256, 0, stream>>>(Qb, Kb, Vb, biasF, out);
}

// Round 8
// 300.593 us; speedup vs baseline: 1.3323x; 1.3323x over previous
//
#include <hip/hip_runtime.h>

using f32x4  = __attribute__((ext_vector_type(4))) float;
using bf16x8 = __attribute__((ext_vector_type(8))) short;

#define SEQ 1025
#define NH  12

__device__ __forceinline__ unsigned short f2bf(float f) {
  unsigned u = __float_as_uint(f);
  u += 0x7FFFu + ((u >> 16) & 1u);        // RNE; inputs are finite
  return (unsigned short)(u >> 16);
}

// cheap round-to-nearest (ties up) for P values (p >= 0, feeds PV MFMA)
__device__ __forceinline__ unsigned short f2bf_p(float f) {
  return (unsigned short)((__float_as_uint(f) + 0x8000u) >> 16);
}

__device__ __forceinline__ void async16(const void* g, void* s) {
  __builtin_amdgcn_global_load_lds(
      (const __attribute__((address_space(1))) void*)g,
      (__attribute__((address_space(3))) void*)s, 16, 0, 0);
}

// ================= device bodies ============================================

// ---- X fp32 -> bf16, padded to 8320 rows (zeros) ----
__device__ __forceinline__ void conv_x_body(int bx, const float* __restrict__ X,
                                            ushort* __restrict__ Xb) {
  int t = bx * 256 + threadIdx.x;
  if (t >= 8320 * 96) return;
  int row = t / 96;
  size_t e = (size_t)t * 8;
  union { uint4 q; ushort us[8]; } o;
  if (row < 8200) {
    float4 f0 = *(const float4*)(X + e);
    float4 f1 = *(const float4*)(X + e + 4);
    o.us[0] = f2bf(f0.x); o.us[1] = f2bf(f0.y); o.us[2] = f2bf(f0.z); o.us[3] = f2bf(f0.w);
    o.us[4] = f2bf(f1.x); o.us[5] = f2bf(f1.y); o.us[6] = f2bf(f1.z); o.us[7] = f2bf(f1.w);
  } else {
    o.q = make_uint4(0, 0, 0, 0);
  }
  *(uint4*)(Xb + e) = o.q;
}

// ---- W[q|k|v] fp32 -> Wt [N=2304][K=768] bf16 (+ bias fold) ----
__device__ __forceinline__ void pack_w_body(int j, const float* __restrict__ Wq,
                                            const float* __restrict__ Wk,
                                            const float* __restrict__ Wv,
                                            ushort* __restrict__ Wt,
                                            const float* __restrict__ bq,
                                            const float* __restrict__ bk,
                                            const float* __restrict__ bv,
                                            float* __restrict__ bc,
                                            float (*tile)[33]) {
  const int nt = j % 72;                       // 0..71
  const int kt = j / 72;                       // 0..23
  if (kt == 0 && nt < 9) {                     // folded bias concat
    int t2 = nt * 256 + threadIdx.x;
    if (t2 < 768) bc[t2] = bq[t2];
    else if (t2 < 1536) bc[t2] = bk[t2 - 768];
    else if (t2 < 2304) bc[t2] = bv[t2 - 1536];
  }
  const int sel = nt / 24;
  const int o0 = (nt - sel * 24) * 32;
  const int k0 = kt * 32;
  const float* W = sel == 0 ? Wq : sel == 1 ? Wk : Wv;
  const int t = threadIdx.x;
  const int x = t & 31, y = t >> 5;
  for (int p = 0; p < 4; ++p)
    tile[y + p * 8][x] = W[(size_t)(k0 + y + p * 8) * 768 + o0 + x];
  __syncthreads();
  for (int p = 0; p < 4; ++p) {
    const int nl = y + p * 8;
    Wt[(size_t)(nt * 32 + nl) * 768 + k0 + x] = f2bf(tile[x][nl]);
  }
}

// ---- rel_bias repack: [H][S][S] -> MFMA C-frag order -----------------------
// biasF[h][kt=17][w16=72][lane=64][e=16], e=ct*4+r2, pre-scaled by log2(e),
// cols>1024 pre-masked to -3e30.
__device__ __forceinline__ void repack_body(int id, const float* __restrict__ rel,
                                            float* __restrict__ bf,
                                            float (*lds)[580]) {
  const int half = id & 1;
  const int hw = id >> 1;
  const int h = hw / 72, w = hw - h * 72;
  const int t = threadIdx.x;
  const int W = half ? 512 : 576;              // kt 9..16 : kt 0..8
  const int cbase = half * 576;
  const float* src = rel + (size_t)h * SEQ * SEQ;
  for (int r = 0; r < 16; ++r) {
    int q = w * 16 + r; if (q > 1024) q = 1024;
    const float* row = src + (size_t)q * SEQ;
    for (int c = t; c < W; c += 256) {
      int col = cbase + c;
      lds[r][c] = (col <= 1024) ? row[col] * 1.44269504f : -3.0e30f;
    }
  }
  __syncthreads();
  const int lane = t >> 2, ct = t & 3;
  const int l16 = lane & 15, quad = lane >> 4;
  const int nkt = half ? 8 : 9;
  for (int ktl = 0; ktl < nkt; ++ktl) {
    const int kt = half * 9 + ktl;
    const int col = ktl * 64 + ct * 16 + l16;
    f32x4 v;
    v[0] = lds[quad * 4 + 0][col];
    v[1] = lds[quad * 4 + 1][col];
    v[2] = lds[quad * 4 + 2][col];
    v[3] = lds[quad * 4 + 3][col];
    *(f32x4*)(bf + (((size_t)h * 17 + kt) * 72 + w) * 1024 + lane * 16 + ct * 4) = v;
  }
}

// ---- fused QKV GEMM tile: [8320x768]*[768x2304] -> Q/K/V [B,H,S,64] bf16 ---
// smem layout: a_sm[0,8192) b_sm[8192,16384) c_sm[16384,33792)
__device__ __forceinline__ void gemm_body(int mb, int nb,
                                          const ushort* __restrict__ A,
                                          const ushort* __restrict__ Bt,
                                          const float* __restrict__ bias,
                                          ushort* __restrict__ Qo,
                                          ushort* __restrict__ Ko,
                                          ushort* __restrict__ Vo,
                                          char* smem) {
  ushort* a_sm = (ushort*)smem;
  ushort* b_sm = (ushort*)(smem + 8192);
  ushort* c_sm = (ushort*)(smem + 16384);      // 64 x 136
  const int t = threadIdx.x;
  const int lane = t & 63, wave = t >> 6;
  const int quad = lane >> 4, l16 = lane & 15;
  const int wrow = wave >> 1, wcol = wave & 1;
  const int m0 = mb * 128, n0 = nb * 128;

  f32x4 acc[4][4] = {};

  const ushort* a_g = A + (size_t)m0 * 768;
  const ushort* b_g = Bt + (size_t)n0 * 768;

  for (int k0 = 0; k0 < 768; k0 += 32) {
    __syncthreads();
    for (int r = 0; r < 2; ++r) {
      int c = r * 256 + t;
      int row = c >> 2;
      int colb = (c & 3) * 16;
      async16((const char*)(a_g + (size_t)row * 768 + k0) + colb, (char*)a_sm + c * 16);
      async16((const char*)(b_g + (size_t)row * 768 + k0) + colb, (char*)b_sm + c * 16);
    }
    __syncthreads();
    bf16x8 af[4], bfr[4];
    for (int i = 0; i < 4; ++i) {
      af[i]  = *(const bf16x8*)(a_sm + (wrow * 64 + i * 16 + l16) * 32 + quad * 8);
      bfr[i] = *(const bf16x8*)(b_sm + (wcol * 64 + i * 16 + l16) * 32 + quad * 8);
    }
    for (int i = 0; i < 4; ++i)
      for (int j = 0; j < 4; ++j)
        acc[i][j] = __builtin_amdgcn_mfma_f32_16x16x32_bf16(af[i], bfr[j], acc[i][j], 0, 0, 0);
  }

  // epilogue: n-tile (128) lies in one of Q/K/V and spans 2 heads
  const int sel = n0 / 768;
  const int o0 = n0 - sel * 768;
  const int hh0 = o0 >> 6;
  ushort* dst = sel == 0 ? Qo : sel == 1 ? Ko : Vo;
  float bvj[4];
  for (int j = 0; j < 4; ++j) bvj[j] = bias[n0 + wcol * 64 + j * 16 + l16];

  for (int p = 0; p < 2; ++p) {
    __syncthreads();
    if (wrow == p) {
      for (int i = 0; i < 4; ++i)
        for (int j = 0; j < 4; ++j)
          for (int r = 0; r < 4; ++r)
            c_sm[(i * 16 + quad * 4 + r) * 136 + wcol * 64 + j * 16 + l16] =
                f2bf(acc[i][j][r] + bvj[j]);
    }
    __syncthreads();
    const int head = t >> 7;
    const int ci = t & 127;
    for (int k = 0; k < 4; ++k) {
      int ch = ci + 128 * k;
      int row = ch >> 3, off = (ch & 7) * 8;
      int gm = m0 + p * 64 + row;
      if (gm < 8200) {
        int bb = gm / 1025, ss = gm - bb * 1025;
        uint4 v = *(const uint4*)(c_sm + row * 136 + head * 64 + off);
        *(uint4*)(dst + (((size_t)(bb * NH + hh0 + head) * SEQ + ss) << 6) + off) = v;
      }
    }
  }
}

// ================= kernels ==================================================

// prep: conv_x (3120 blocks) + pack_w/bias fold (1728 blocks)
__global__ __launch_bounds__(256) void prep(const float* __restrict__ X,
                                            ushort* __restrict__ Xb,
                                            const float* __restrict__ Wq,
                                            const float* __restrict__ Wk,
                                            const float* __restrict__ Wv,
                                            ushort* __restrict__ Wt,
                                            const float* __restrict__ bq,
                                            const float* __restrict__ bk,
                                            const float* __restrict__ bv,
                                            float* __restrict__ bc) {
  __shared__ __align__(16) float tile[32][33];
  const int bx = blockIdx.x;
  if (bx < 3120) conv_x_body(bx, X, Xb);
  else pack_w_body(bx - 3120, Wq, Wk, Wv, Wt, bq, bk, bv, bc, tile);
}

// merged gemm (1296 slots, XCD-swizzled 65x18 tiles + 126 no-ops) +
// bias repack (1728 blocks). XCD x = bx&7 owns a contiguous m-range
// (x=0: m 0..8, else 8 tiles), n fastest -> per-XCD L2 holds its A slice
// (~1.8 MB) + B (3.5 MB): global_load_lds drains hit L2 (~200cyc) not HBM.
__global__ __launch_bounds__(256, 4) void gemm_repack(
    const ushort* __restrict__ A, const ushort* __restrict__ Bt,
    const float* __restrict__ biasc, ushort* __restrict__ Qo,
    ushort* __restrict__ Ko, ushort* __restrict__ Vo,
    const float* __restrict__ rel, float* __restrict__ bf) {
  __shared__ __align__(16) char smem[37120];
  const int bx = blockIdx.x;
  if (bx < 1296) {
    const int x = bx & 7, k = bx >> 3;         // k in 0..161
    const int ml = k / 18, n = k - ml * 18;
    int m;
    if (x == 0) m = ml;                        // 9 tiles: 0..8
    else { if (ml >= 8) return; m = 9 + (x - 1) * 8 + ml; }
    gemm_body(m, n, A, Bt, biasc, Qo, Ko, Vo, smem);
  } else {
    repack_body(bx - 1296, rel, bf, (float(*)[580])smem);
  }
}

// standalone fallbacks (layout B: biasF overlays Xb -> repack must follow gemm)
__global__ __launch_bounds__(256) void gemm_qkv_k(const ushort* __restrict__ A,
                                                  const ushort* __restrict__ Bt,
                                                  const float* __restrict__ biasc,
                                                  ushort* __restrict__ Qo,
                                                  ushort* __restrict__ Ko,
                                                  ushort* __restrict__ Vo) {
  __shared__ __align__(16) char smem[33792];
  gemm_body(blockIdx.x, blockIdx.y, A, Bt, biasc, Qo, Ko, Vo, smem);
}

__global__ __launch_bounds__(256, 4) void repack_k(const float* __restrict__ rel,
                                                   float* __restrict__ bf) {
  __shared__ __align__(16) float lds[16][580];
  repack_body(blockIdx.x, rel, bf, lds);
}

// ---------------- flash attention (r6-exact: JIT bias, no reg prefetch) -----
// block = 4 waves, one (b,h), 128 q-rows, k-tile 64, 17 iters. K/V register-
// prefetched one tile ahead; bias JIT from C-frag-ordered biasF (8 dwordx4/
// lane/iter, wave-contiguous). r7's bias reg-prefetch spilled to scratch
// (WRITE 31->261 MB) -- do NOT extend prefetch live ranges here.
// LDS: p 4x[32][72] | K [64][72] | V^T [64][72] = 36864 -> 4 blk/CU.
__global__ __launch_bounds__(256, 4) void attn(const ushort* __restrict__ Qb,
                                               const ushort* __restrict__ Kb,
                                               const ushort* __restrict__ Vb,
                                               const float* __restrict__ biasF,
                                               float* __restrict__ out) {
  __shared__ __align__(16) char smem[36864];
  ushort* p_sm = (ushort*)smem;                 // 4 x [32][72]
  ushort* k_sm = (ushort*)(smem + 18432);       // [64][72]
  ushort* v_sm = (ushort*)(smem + 27648);       // [64][72] transposed [hd][k]

  const int t = threadIdx.x;
  const int lane = t & 63, wave = t >> 6;
  const int quad = lane >> 4, l16 = lane & 15;

  const int id = blockIdx.x;                    // [0,864)
  const int x = id & 7, s = id >> 3;            // XCD swizzle
  const int Gg = s / 9, qt = s - Gg * 9;
  const int G = Gg * 8 + x;                     // (b,h) group
  const int b = G / 12, h = G - b * 12;
  const int q0 = qt * 128;

  const size_t bh = (size_t)(b * NH + h) * SEQ * 64;
  const ushort* Qp = Qb + bh;
  const ushort* Kp = Kb + bh;
  const ushort* Vp = Vb + bh;

  uint4 kpre0, kpre1, vpre0, vpre1;
  const int vkp2 = t & 31, vhb = (t >> 5) * 8;

  auto issue_kv = [&](int kb) {
    {
      int c = t, row = c >> 3, cb = (c & 7) * 8;
      int rk = kb + row; if (rk > 1024) rk = 1024;
      kpre0 = *(const uint4*)(Kp + (size_t)rk * 64 + cb);
    }
    {
      int c = t + 256, row = c >> 3, cb = (c & 7) * 8;
      int rk = kb + row; if (rk > 1024) rk = 1024;
      kpre1 = *(const uint4*)(Kp + (size_t)rk * 64 + cb);
    }
    {
      int r0 = kb + vkp2 * 2;
      int r0c = r0 > 1024 ? 1024 : r0;
      int r1c = r0 + 1 > 1024 ? 1024 : r0 + 1;
      vpre0 = *(const uint4*)(Vp + (size_t)r0c * 64 + vhb);
      vpre1 = *(const uint4*)(Vp + (size_t)r1c * 64 + vhb);
    }
  };

  issue_kv(0);

  ushort* pw = p_sm + wave * (32 * 72);
  const int qbase = q0 + wave * 32;
  for (int i = 0; i < 4; ++i) {
    int c = lane + 64 * i;
    int row = c >> 3, cb = (c & 7) * 8;
    int rq = qbase + row; if (rq > 1024) rq = 1024;
    *(uint4*)(pw + row * 72 + cb) = *(const uint4*)(Qp + (size_t)rq * 64 + cb);
  }
  bf16x8 qf[2][2];
  for (int rt = 0; rt < 2; ++rt)
    for (int ks = 0; ks < 2; ++ks)
      qf[rt][ks] = *(const bf16x8*)(pw + (rt * 16 + l16) * 72 + ks * 32 + quad * 8);

  float lst[8] = {0, 0, 0, 0, 0, 0, 0, 0};
  f32x4 oacc[2][4] = {};
  const float c_scale = 0.18033688f;            // (1/8) * log2(e)
  const float* bf_base = biasF +
      ((size_t)h * 17 * 72 + (qt * 8 + wave * 2)) * 1024 + (lane << 4);

  for (int kt = 0; kt < 17; ++kt) {
    __syncthreads();
    {
      int c = t;
      *(uint4*)(k_sm + (c >> 3) * 72 + (c & 7) * 8) = kpre0;
      c = t + 256;
      *(uint4*)(k_sm + (c >> 3) * 72 + (c & 7) * 8) = kpre1;
    }
    {
      union { uint4 q; ushort us[8]; } e0, e1;
      e0.q = vpre0; e1.q = vpre1;
      for (int e = 0; e < 8; ++e)
        *(unsigned*)(v_sm + (vhb + e) * 72 + vkp2 * 2) =
            (unsigned)e0.us[e] | ((unsigned)e1.us[e] << 16);
    }
    __syncthreads();

    const float* bfp = bf_base + (size_t)kt * (72 * 1024);
    f32x4 br[2][4];
    for (int rt = 0; rt < 2; ++rt)
      for (int ct = 0; ct < 4; ++ct)
        br[rt][ct] = *(const f32x4*)(bfp + rt * 1024 + ct * 4);

    if (kt < 16) issue_kv(kt * 64 + 64);

    f32x4 sc[2][4] = {};
    for (int ct = 0; ct < 4; ++ct)
      for (int ks = 0; ks < 2; ++ks) {
        bf16x8 kf = *(const bf16x8*)(k_sm + (ct * 16 + l16) * 72 + ks * 32 + quad * 8);
        sc[0][ct] = __builtin_amdgcn_mfma_f32_16x16x32_bf16(qf[0][ks], kf, sc[0][ct], 0, 0, 0);
        sc[1][ct] = __builtin_amdgcn_mfma_f32_16x16x32_bf16(qf[1][ks], kf, sc[1][ct], 0, 0, 0);
      }

    for (int rt = 0; rt < 2; ++rt)
      for (int ct = 0; ct < 4; ++ct)
        for (int r2 = 0; r2 < 4; ++r2) {
          float p = __builtin_amdgcn_exp2f(
              fmaf(sc[rt][ct][r2], c_scale, br[rt][ct][r2]));
          lst[rt * 4 + r2] += p;
          pw[(rt * 16 + quad * 4 + r2) * 72 + ct * 16 + l16] = f2bf_p(p);
        }

    for (int ks = 0; ks < 2; ++ks) {
      bf16x8 pf0 = *(const bf16x8*)(pw + l16 * 72 + ks * 32 + quad * 8);
      bf16x8 pf1 = *(const bf16x8*)(pw + (16 + l16) * 72 + ks * 32 + quad * 8);
      for (int c4 = 0; c4 < 4; ++c4) {
        bf16x8 vf = *(const bf16x8*)(v_sm + (c4 * 16 + l16) * 72 + ks * 32 + quad * 8);
        oacc[0][c4] = __builtin_amdgcn_mfma_f32_16x16x32_bf16(pf0, vf, oacc[0][c4], 0, 0, 0);
        oacc[1][c4] = __builtin_amdgcn_mfma_f32_16x16x32_bf16(pf1, vf, oacc[1][c4], 0, 0, 0);
      }
    }
  }

  for (int si = 0; si < 8; ++si) {
    float s2 = lst[si];
    s2 += __shfl_xor(s2, 1);
    s2 += __shfl_xor(s2, 2);
    s2 += __shfl_xor(s2, 4);
    s2 += __shfl_xor(s2, 8);
    lst[si] = s2;
  }
  for (int rt = 0; rt < 2; ++rt)
    for (int r2 = 0; r2 < 4; ++r2) {
      int sr = qbase + rt * 16 + quad * 4 + r2;
      if (sr < SEQ) {
        float inv = 1.0f / lst[rt * 4 + r2];
        float* op = out + ((size_t)b * SEQ + sr) * 768 + h * 64;
        for (int c4 = 0; c4 < 4; ++c4)
          op[c4 * 16 + l16] = oacc[rt][c4][r2] * inv;
      }
    }
}

// ---------------- launch ----------------
extern "C" void kernel_launch(void* const* d_in, const int* in_sizes, int n_in,
                              void* d_out, int out_size, void* d_ws, size_t ws_size,
                              hipStream_t stream) {
  const float* X  = (const float*)d_in[0];
  const float* rb = (const float*)d_in[1];
  const float* Wq = (const float*)d_in[2];
  const float* bq = (const float*)d_in[3];
  const float* Wk = (const float*)d_in[4];
  const float* bk = (const float*)d_in[5];
  const float* Wv = (const float*)d_in[6];
  const float* bv = (const float*)d_in[7];
  float* out = (float*)d_out;
  char* ws = (char*)d_ws;

  ushort* Qb    = (ushort*)ws;                          // 12,595,200 B
  ushort* Kb    = (ushort*)(ws + 12595200);
  ushort* Vb    = (ushort*)(ws + 25190400);             // ends 37,785,600
  ushort* Xb    = (ushort*)(ws + 37785600);             // 12,779,520 -> 50,565,120
  ushort* Wt    = (ushort*)(ws + 50565120);             //  3,538,944 -> 54,104,064
  float*  biasc = (float*)(ws + 54104064);              //      9,216 -> 54,113,280

  const bool bigws = ws_size >= 114275328ULL;
  // layout A: biasF in fresh space (repack can overlap gemm);
  // layout B: biasF overlays Xb/Wt (dead after gemm) -> repack after gemm.
  float* biasF = bigws ? (float*)(ws + 54113280) : (float*)(ws + 37785600);

  prep<<<3120 + 1728, 256, 0, stream>>>(X, Xb, Wq, Wk, Wv, Wt, bq, bk, bv, biasc);
  if (bigws) {
    gemm_repack<<<1296 + 1728, 256, 0, stream>>>(Xb, Wt, biasc, Qb, Kb, Vb, rb, biasF);
  } else {
    gemm_qkv_k<<<dim3(65, 18), 256, 0, stream>>>(Xb, Wt, biasc, Qb, Kb, Vb);
    repack_k<<<NH * 72 * 2, 256, 0, stream>>>(rb, biasF);
  }
  attn<<<864, 256, 0, stream>>>(Qb, Kb, Vb, biasF, out);
}